// Round 15
// baseline (321.691 us; speedup 1.0000x reference)
//
#include <hip/hip_runtime.h>
#include <cmath>

#define T_    128
#define F_    64
#define DI    512
#define DS    16
#define NROW  16384   // 128 seqs * 128 t

// workspace layout (float offsets)
#define U_OFF    0u
#define SRES_OFF 8388608u                 // NROW*DI
#define DPH_OFF  16777216u                // NROW*32 (dlt, then dph)
#define DPT_OFF  17301504u                // NROW
#define B_OFF    17317888u                // NROW*16
#define C_OFF    17580032u                // NROW*16
#define DAT_OFF  17842176u                // NROW*16 (precomputed tail exp(dpt*A))
// end = 18104320 floats (~72.4 MB)

__device__ __forceinline__ float silu_f(float v)    { return v / (1.f + __expf(-v)); }
__device__ __forceinline__ float softplus_f(float v){ return (v > 20.f) ? v : log1pf(__expf(v)); }

// ---------------------------------------------------------------------------
// K1 (r5-verified, ~53us): xz = X @ W_in + causal depthwise conv4 + SiLU.
// float4 columns, 8-row t-tile, 4+4-row W ping-pong (~76 VGPR).
// ---------------------------------------------------------------------------
__global__ __launch_bounds__(256) void k1_inproj(
    const float* __restrict__ x, const float* __restrict__ W_in,
    const float* __restrict__ W_conv, const float* __restrict__ b_conv,
    float* __restrict__ u, float* __restrict__ sres)
{
    __shared__ float x_l[11][64];
    const int s   = blockIdx.y;
    const int t0  = blockIdx.x * 8;
    const int tid = threadIdx.x;
    const int c4  = tid * 4;                // column 0..1023

    if (tid < 11 * 16) {
        const int row = tid >> 4, cc = (tid & 15) * 4;
        const int trow = t0 - 3 + row;
        float4 v = make_float4(0.f, 0.f, 0.f, 0.f);
        if (trow >= 0) v = *(const float4*)&x[(size_t)s * (T_ * F_) + trow * F_ + cc];
        *(float4*)&x_l[row][cc] = v;
    }
    __syncthreads();

    float4 acc[11];
#pragma unroll
    for (int i = 0; i < 11; ++i) acc[i] = make_float4(0.f, 0.f, 0.f, 0.f);

    auto compute4 = [&](int f0, const float4 (&wv)[4]) {
#pragma unroll
        for (int tt = 0; tt < 11; ++tt) {
            const float4 xa = *(const float4*)&x_l[tt][f0];
            float4 a = acc[tt];
            a.x = fmaf(xa.x, wv[0].x, a.x); a.y = fmaf(xa.x, wv[0].y, a.y);
            a.z = fmaf(xa.x, wv[0].z, a.z); a.w = fmaf(xa.x, wv[0].w, a.w);
            a.x = fmaf(xa.y, wv[1].x, a.x); a.y = fmaf(xa.y, wv[1].y, a.y);
            a.z = fmaf(xa.y, wv[1].z, a.z); a.w = fmaf(xa.y, wv[1].w, a.w);
            a.x = fmaf(xa.z, wv[2].x, a.x); a.y = fmaf(xa.z, wv[2].y, a.y);
            a.z = fmaf(xa.z, wv[2].z, a.z); a.w = fmaf(xa.z, wv[2].w, a.w);
            a.x = fmaf(xa.w, wv[3].x, a.x); a.y = fmaf(xa.w, wv[3].y, a.y);
            a.z = fmaf(xa.w, wv[3].z, a.z); a.w = fmaf(xa.w, wv[3].w, a.w);
            acc[tt] = a;
        }
    };

    float4 wa[4], wb[4];
#pragma unroll
    for (int j = 0; j < 4; ++j) wa[j] = *(const float4*)&W_in[(size_t)j * 1024 + c4];
    for (int k0 = 0; k0 < 64; k0 += 8) {
#pragma unroll
        for (int j = 0; j < 4; ++j) wb[j] = *(const float4*)&W_in[(size_t)(k0 + 4 + j) * 1024 + c4];
        compute4(k0, wa);
        if (k0 + 8 < 64) {
#pragma unroll
            for (int j = 0; j < 4; ++j) wa[j] = *(const float4*)&W_in[(size_t)(k0 + 8 + j) * 1024 + c4];
        }
        compute4(k0 + 4, wb);
    }

    if (c4 < DI) {
        const float4 wk0 = *(const float4*)&W_conv[(c4 + 0) * 4];
        const float4 wk1 = *(const float4*)&W_conv[(c4 + 1) * 4];
        const float4 wk2 = *(const float4*)&W_conv[(c4 + 2) * 4];
        const float4 wk3 = *(const float4*)&W_conv[(c4 + 3) * 4];
        const float4 bc  = *(const float4*)&b_conv[c4];
#pragma unroll
        for (int i = 0; i < 8; ++i) {
            float4 pre;
            pre.x = bc.x; pre.y = bc.y; pre.z = bc.z; pre.w = bc.w;
            pre.x = fmaf(wk0.x, acc[i].x, pre.x); pre.x = fmaf(wk0.y, acc[i+1].x, pre.x);
            pre.x = fmaf(wk0.z, acc[i+2].x, pre.x); pre.x = fmaf(wk0.w, acc[i+3].x, pre.x);
            pre.y = fmaf(wk1.x, acc[i].y, pre.y); pre.y = fmaf(wk1.y, acc[i+1].y, pre.y);
            pre.y = fmaf(wk1.z, acc[i+2].y, pre.y); pre.y = fmaf(wk1.w, acc[i+3].y, pre.y);
            pre.z = fmaf(wk2.x, acc[i].z, pre.z); pre.z = fmaf(wk2.y, acc[i+1].z, pre.z);
            pre.z = fmaf(wk2.z, acc[i+2].z, pre.z); pre.z = fmaf(wk2.w, acc[i+3].z, pre.z);
            pre.w = fmaf(wk3.x, acc[i].w, pre.w); pre.w = fmaf(wk3.y, acc[i+1].w, pre.w);
            pre.w = fmaf(wk3.z, acc[i+2].w, pre.w); pre.w = fmaf(wk3.w, acc[i+3].w, pre.w);
            float4 o;
            o.x = silu_f(pre.x); o.y = silu_f(pre.y);
            o.z = silu_f(pre.z); o.w = silu_f(pre.w);
            *(float4*)&u[(size_t)(s * T_ + t0 + i) * DI + c4] = o;
        }
    } else {
        const int c = c4 - DI;
#pragma unroll
        for (int i = 0; i < 8; ++i) {
            float4 o;
            o.x = silu_f(acc[i + 3].x); o.y = silu_f(acc[i + 3].y);
            o.z = silu_f(acc[i + 3].z); o.w = silu_f(acc[i + 3].w);
            *(float4*)&sres[(size_t)(s * T_ + t0 + i) * DI + c] = o;
        }
    }
}

// ---------------------------------------------------------------------------
// K2a (v1, r5-verified, ~43us): xdbl = u @ W_xproj -> dlt / B / C. 32-row
// tiles, 512 blocks x 128 thr, KC=64 LDS double-buffer + reg staging.
// ---------------------------------------------------------------------------
__global__ __launch_bounds__(128) void k2a_xproj(
    const float* __restrict__ uin, const float* __restrict__ W_xp,
    float* __restrict__ dlt, float* __restrict__ Bb, float* __restrict__ Cb)
{
    __shared__ float y_l[2][32][68];
    __shared__ float w_l[2][64][64];
    const int tid = threadIdx.x;
    const int rq = tid >> 4, cq = tid & 15;
    const int r0 = blockIdx.x * 32;
    const int c4 = cq * 4;

    float4 yR[4], wR[8];
    auto ld = [&](int kc) {
#pragma unroll
        for (int q = 0; q < 4; ++q) {
            const int i = q * 128 + tid;
            yR[q] = *(const float4*)&uin[(size_t)(r0 + (i >> 4)) * DI + kc + (i & 15) * 4];
        }
#pragma unroll
        for (int q = 0; q < 8; ++q) {
            const int i = q * 128 + tid;
            wR[q] = *(const float4*)&W_xp[(size_t)(kc + (i >> 4)) * 64 + (i & 15) * 4];
        }
    };
    auto st = [&](int b) {
#pragma unroll
        for (int q = 0; q < 4; ++q) {
            const int i = q * 128 + tid;
            *(float4*)&y_l[b][i >> 4][(i & 15) * 4] = yR[q];
        }
#pragma unroll
        for (int q = 0; q < 8; ++q) {
            const int i = q * 128 + tid;
            *(float4*)&w_l[b][i >> 4][(i & 15) * 4] = wR[q];
        }
    };

    float4 acc[4];
#pragma unroll
    for (int i = 0; i < 4; ++i) acc[i] = make_float4(0.f, 0.f, 0.f, 0.f);

    ld(0); st(0); __syncthreads();
    for (int t8 = 0; t8 < 8; ++t8) {
        const int b = t8 & 1;
        if (t8 < 7) ld((t8 + 1) * 64);
#pragma unroll 4
        for (int kk = 0; kk < 64; kk += 4) {
            float4 yv[4], wv[4];
#pragma unroll
            for (int i = 0; i < 4; ++i) yv[i] = *(const float4*)&y_l[b][rq * 4 + i][kk];
#pragma unroll
            for (int j = 0; j < 4; ++j) wv[j] = *(const float4*)&w_l[b][kk + j][c4];
#pragma unroll
            for (int i = 0; i < 4; ++i) {
                float4 a = acc[i];
                a.x = fmaf(yv[i].x, wv[0].x, a.x); a.y = fmaf(yv[i].x, wv[0].y, a.y);
                a.z = fmaf(yv[i].x, wv[0].z, a.z); a.w = fmaf(yv[i].x, wv[0].w, a.w);
                a.x = fmaf(yv[i].y, wv[1].x, a.x); a.y = fmaf(yv[i].y, wv[1].y, a.y);
                a.z = fmaf(yv[i].y, wv[1].z, a.z); a.w = fmaf(yv[i].y, wv[1].w, a.w);
                a.x = fmaf(yv[i].z, wv[2].x, a.x); a.y = fmaf(yv[i].z, wv[2].y, a.y);
                a.z = fmaf(yv[i].z, wv[2].z, a.z); a.w = fmaf(yv[i].z, wv[2].w, a.w);
                a.x = fmaf(yv[i].w, wv[3].x, a.x); a.y = fmaf(yv[i].w, wv[3].y, a.y);
                a.z = fmaf(yv[i].w, wv[3].z, a.z); a.w = fmaf(yv[i].w, wv[3].w, a.w);
                acc[i] = a;
            }
        }
        if (t8 < 7) st(1 - b);
        __syncthreads();
    }
#pragma unroll
    for (int i = 0; i < 4; ++i) {
        const int r = r0 + rq * 4 + i;
        if (c4 < 32)      *(float4*)&dlt[(size_t)r * 32 + c4]        = acc[i];
        else if (c4 < 48) *(float4*)&Bb [(size_t)r * DS + (c4 - 32)] = acc[i];
        else              *(float4*)&Cb [(size_t)r * DS + (c4 - 48)] = acc[i];
    }
}

// ---------------------------------------------------------------------------
// K2b v2 (r10-verified, ~21us): row-split x4, 2048 blocks x 8 rows.
// ---------------------------------------------------------------------------
__global__ __launch_bounds__(256) void k2b_delta(
    const float* __restrict__ dlt_in, const float* __restrict__ W_dt,
    const float* __restrict__ b_dt, const int* __restrict__ adj,
    const float* __restrict__ A_log,
    float* __restrict__ dph, float* __restrict__ dpt, float* __restrict__ dAt)
{
    __shared__ float dl_l[8][32];
    __shared__ float head_l[8][33];
    __shared__ float scrS[4][8];
    __shared__ float st_l[8], stail_l[8];
    __shared__ float adj_l[1024];

    const int tid  = threadIdx.x;
    const int lane = tid & 63, wv4 = tid >> 6;
    const int r0   = blockIdx.x * 8;

    dl_l[tid >> 5][tid & 31] = dlt_in[(size_t)(r0 + (tid >> 5)) * 32 + (tid & 31)];
    for (int i = tid; i < 1024; i += 256) adj_l[i] = (float)adj[i];

    float wdt0[32], wdt1[32];
#pragma unroll
    for (int j = 0; j < 32; ++j) {
        wdt0[j] = W_dt[j * DI + tid];
        wdt1[j] = W_dt[j * DI + tid + 256];
    }
    const float b0 = b_dt[tid], b1 = b_dt[tid + 256];
    __syncthreads();

    for (int r = 0; r < 8; ++r) {
        float a0 = b0, a1 = b1;
#pragma unroll
        for (int jq = 0; jq < 8; ++jq) {
            const float4 dv = *(const float4*)&dl_l[r][jq * 4];
            a0 = fmaf(dv.x, wdt0[jq*4+0], a0); a1 = fmaf(dv.x, wdt1[jq*4+0], a1);
            a0 = fmaf(dv.y, wdt0[jq*4+1], a0); a1 = fmaf(dv.y, wdt1[jq*4+1], a1);
            a0 = fmaf(dv.z, wdt0[jq*4+2], a0); a1 = fmaf(dv.z, wdt1[jq*4+2], a1);
            a0 = fmaf(dv.w, wdt0[jq*4+3], a0); a1 = fmaf(dv.w, wdt1[jq*4+3], a1);
        }
        const float e0 = softplus_f(a0), e1 = softplus_f(a1);
        if (tid < 32) head_l[r][tid] = e0;
        float v = e0 + e1;
#pragma unroll
        for (int off = 32; off > 0; off >>= 1) v += __shfl_down(v, off, 64);
        if (lane == 0) scrS[wv4][r] = v;
    }
    __syncthreads();
    if (tid < 8) {
        const int r = tid;
        const float st = scrS[0][r] + scrS[1][r] + scrS[2][r] + scrS[3][r];
        dpt[r0 + r] = st;
        float sh = 0.f;
#pragma unroll
        for (int j = 0; j < 32; ++j) sh += head_l[r][j];
        st_l[r] = st;
        stail_l[r] = st - sh;
    }
    __syncthreads();
    {   // dph: 8 rows x 32 cols, one per thread
        const int r = tid >> 5, dd = tid & 31;
        float a = stail_l[r];
#pragma unroll
        for (int j = 0; j < 32; ++j) a = fmaf(head_l[r][j], adj_l[j * 32 + dd], a);
        dph[(size_t)(r0 + r) * 32 + dd] = a;
    }
    if (tid < 128) {   // dAt: 8 rows x 16 states
        const int r = tid >> 4, n = tid & 15;
        dAt[(size_t)(r0 + r) * DS + n] = __expf(st_l[r] * (-__expf(A_log[n])));
    }
}

// ---------------------------------------------------------------------------
// K3 v3: n-split x8, 32-channel groups. Each thread owns 2 of 16 states of
// one channel; octet reduce = 3 shfl_xor. Grid dim3(16,128) = 2048 blocks x
// 4 waves = 8 blocks/CU = 32 waves/CU (2x the r2 version's 16) — the chunk
// loop's exposed HBM latency now has 8 waves/SIMD to hide behind. LDS 9.3KB.
// grp==0 is exactly the 32 head channels -> head/tail branch block-uniform.
// Plain launch_bounds (no min-waves hint: r3 spill lesson).
// ---------------------------------------------------------------------------
#define CH 8
__global__ __launch_bounds__(256) void k3_scan(
    const float* __restrict__ u, float* __restrict__ sres_y,
    const float* __restrict__ dph, const float* __restrict__ dpt,
    const float* __restrict__ Bb, const float* __restrict__ Cb,
    const float* __restrict__ dAt, const float* __restrict__ A_log,
    const float* __restrict__ Dvec)
{
    __shared__ __align__(16) float u_s[2][CH][32];      // 2 KB
    __shared__ __align__(16) float g_s[2][CH][32];      // 2 KB
    __shared__ __align__(16) float B_s[2][CH][16];      // 1 KB
    __shared__ __align__(16) float C_s[2][CH][16];      // 1 KB
    __shared__ __align__(16) float dAt_s[2][CH][16];    // 1 KB
    __shared__ __align__(16) float dph_s[2][CH][32];    // 2 KB
    __shared__ float dpt_s[2][CH];

    const int tid = threadIdx.x;
    const int s   = blockIdx.y;
    const int grp = blockIdx.x;              // 16 groups of 32 channels
    const int dc  = tid >> 3;                // channel within group (0..31)
    const int nq  = tid & 7;                 // state pair index (0..7)
    const int n0  = nq * 2;                  // this thread's 2 states
    const bool isHead = (grp == 0);          // block-uniform

    const size_t rb = (size_t)s * T_;
    const float* up   = u      + rb * DI + grp * 32;
    float*       gp   = sres_y + rb * DI + grp * 32;
    const float* dphp = dph + rb * 32;
    const float* dptp = dpt + rb;
    const float* Bp   = Bb  + rb * DS;
    const float* Cp   = Cb  + rb * DS;
    const float* dAtp = dAt + rb * DS;

    float2 A0v = make_float2(0.f, 0.f);
    if (isHead) {
        A0v.x = -__expf(A_log[n0 + 0]);
        A0v.y = -__expf(A_log[n0 + 1]);
    }
    const float Dd = Dvec[grp * 32 + dc];

    float h0 = 0.f, h1 = 0.f;

    float4 ugR, bcR, dphR0, dphR1;
    float  dptR;
    auto issue_loads = [&](int c) {
        if (tid < 64) {                          // u: 8 rows x 8 float4
            const int j = tid >> 3, c4 = (tid & 7) * 4;
            ugR = *(const float4*)&up[(size_t)(c * CH + j) * DI + c4];
        } else if (tid < 128) {                  // g: same mapping
            const int t2 = tid - 64;
            const int j = t2 >> 3, c4 = (t2 & 7) * 4;
            ugR = *(const float4*)&gp[(size_t)(c * CH + j) * DI + c4];
        } else if (tid < 160) {                  // B: 8 rows x 4 float4
            const int t2 = tid - 128;
            bcR = *(const float4*)&Bp[(c * CH + (t2 >> 2)) * DS + (t2 & 3) * 4];
        } else if (tid < 192) {                  // C
            const int t2 = tid - 160;
            bcR = *(const float4*)&Cp[(c * CH + (t2 >> 2)) * DS + (t2 & 3) * 4];
        } else if (tid < 224) {                  // dAt
            const int t2 = tid - 192;
            bcR = *(const float4*)&dAtp[(c * CH + (t2 >> 2)) * DS + (t2 & 3) * 4];
        }
        if (isHead && tid >= 224) {              // dph: 8 rows x 8 float4, 2/thread
            const int t2 = tid - 224;            // 0..31
            dphR0 = *(const float4*)&dphp[(size_t)(c * CH + (t2 >> 3)) * 32 + (t2 & 7) * 4];
            const int t3 = t2 + 32;
            dphR1 = *(const float4*)&dphp[(size_t)(c * CH + (t3 >> 3)) * 32 + (t3 & 7) * 4];
        }
        if (tid < CH) dptR = dptp[c * CH + tid];
    };
    auto write_lds = [&](int b) {
        if (tid < 64) {
            const int j = tid >> 3, c4 = (tid & 7) * 4;
            *(float4*)&u_s[b][j][c4] = ugR;
        } else if (tid < 128) {
            const int t2 = tid - 64;
            const int j = t2 >> 3, c4 = (t2 & 7) * 4;
            *(float4*)&g_s[b][j][c4] = ugR;
        } else if (tid < 160) {
            const int t2 = tid - 128;
            *(float4*)&B_s[b][t2 >> 2][(t2 & 3) * 4] = bcR;
        } else if (tid < 192) {
            const int t2 = tid - 160;
            *(float4*)&C_s[b][t2 >> 2][(t2 & 3) * 4] = bcR;
        } else if (tid < 224) {
            const int t2 = tid - 192;
            *(float4*)&dAt_s[b][t2 >> 2][(t2 & 3) * 4] = bcR;
        }
        if (isHead && tid >= 224) {
            const int t2 = tid - 224;
            *(float4*)&dph_s[b][t2 >> 3][(t2 & 7) * 4] = dphR0;
            const int t3 = t2 + 32;
            *(float4*)&dph_s[b][t3 >> 3][(t3 & 7) * 4] = dphR1;
        }
        if (tid < CH) dpt_s[b][tid] = dptR;
    };

    issue_loads(0); write_lds(0); __syncthreads();

    float yr = 0.f;
    for (int c = 0; c < T_ / CH; ++c) {
        const int b = c & 1;
        if (c + 1 < T_ / CH) issue_loads(c + 1);
#pragma unroll
        for (int j = 0; j < CH; ++j) {
            const float uv = u_s[b][j][dc];
            const float gv = g_s[b][j][dc];
            float dp;
            float2 av;
            if (isHead) {
                dp = dph_s[b][j][dc];
                av.x = __expf(dp * A0v.x);
                av.y = __expf(dp * A0v.y);
            } else {
                dp = dpt_s[b][j];
                av = *(const float2*)&dAt_s[b][j][n0];
            }
            const float2 Bv = *(const float2*)&B_s[b][j][n0];
            const float2 Cv = *(const float2*)&C_s[b][j][n0];
            const float du = dp * uv;
            h0 = fmaf(av.x, h0, du * Bv.x); float y = h0 * Cv.x;
            h1 = fmaf(av.y, h1, du * Bv.y); y = fmaf(h1, Cv.y, y);
            y += __shfl_xor(y, 1, 64);           // sum across the 8-lane octet
            y += __shfl_xor(y, 2, 64);
            y += __shfl_xor(y, 4, 64);
            const float yf = fmaf(uv, Dd, y) * gv;
            if (j == nq) yr = yf;                // lane nq keeps timestep j==nq
            if (j == CH - 1) {                   // flush: each lane its own row
                gp[(size_t)(c * CH + nq) * DI + dc] = yr;
            }
        }
        if (c + 1 < T_ / CH) write_lds(1 - b);
        __syncthreads();
    }
}

// ---------------------------------------------------------------------------
// K4 (v1, r5-verified, ~43us): out = y @ W_out. Mirror of k2a v1.
// ---------------------------------------------------------------------------
__global__ __launch_bounds__(128) void k4_out(
    const float* __restrict__ y, const float* __restrict__ W_out,
    float* __restrict__ out)
{
    __shared__ float y_l[2][32][68];
    __shared__ float w_l[2][64][64];
    const int tid = threadIdx.x;
    const int rq = tid >> 4, cq = tid & 15;
    const int r0 = blockIdx.x * 32;
    const int c4 = cq * 4;

    float4 yR[4], wR[8];
    auto ld = [&](int kc) {
#pragma unroll
        for (int q = 0; q < 4; ++q) {
            const int i = q * 128 + tid;
            yR[q] = *(const float4*)&y[(size_t)(r0 + (i >> 4)) * DI + kc + (i & 15) * 4];
        }
#pragma unroll
        for (int q = 0; q < 8; ++q) {
            const int i = q * 128 + tid;
            wR[q] = *(const float4*)&W_out[(size_t)(kc + (i >> 4)) * 64 + (i & 15) * 4];
        }
    };
    auto st = [&](int b) {
#pragma unroll
        for (int q = 0; q < 4; ++q) {
            const int i = q * 128 + tid;
            *(float4*)&y_l[b][i >> 4][(i & 15) * 4] = yR[q];
        }
#pragma unroll
        for (int q = 0; q < 8; ++q) {
            const int i = q * 128 + tid;
            *(float4*)&w_l[b][i >> 4][(i & 15) * 4] = wR[q];
        }
    };

    float4 acc[4];
#pragma unroll
    for (int i = 0; i < 4; ++i) acc[i] = make_float4(0.f, 0.f, 0.f, 0.f);

    ld(0); st(0); __syncthreads();
    for (int t8 = 0; t8 < 8; ++t8) {
        const int b = t8 & 1;
        if (t8 < 7) ld((t8 + 1) * 64);
#pragma unroll 4
        for (int kk = 0; kk < 64; kk += 4) {
            float4 yv[4], wv[4];
#pragma unroll
            for (int i = 0; i < 4; ++i) yv[i] = *(const float4*)&y_l[b][rq * 4 + i][kk];
#pragma unroll
            for (int j = 0; j < 4; ++j) wv[j] = *(const float4*)&w_l[b][kk + j][c4];
#pragma unroll
            for (int i = 0; i < 4; ++i) {
                float4 a = acc[i];
                a.x = fmaf(yv[i].x, wv[0].x, a.x); a.y = fmaf(yv[i].x, wv[0].y, a.y);
                a.z = fmaf(yv[i].x, wv[0].z, a.z); a.w = fmaf(yv[i].x, wv[0].w, a.w);
                a.x = fmaf(yv[i].y, wv[1].x, a.x); a.y = fmaf(yv[i].y, wv[1].y, a.y);
                a.z = fmaf(yv[i].y, wv[1].z, a.z); a.w = fmaf(yv[i].y, wv[1].w, a.w);
                a.x = fmaf(yv[i].z, wv[2].x, a.x); a.y = fmaf(yv[i].z, wv[2].y, a.y);
                a.z = fmaf(yv[i].z, wv[2].z, a.z); a.w = fmaf(yv[i].z, wv[2].w, a.w);
                a.x = fmaf(yv[i].w, wv[3].x, a.x); a.y = fmaf(yv[i].w, wv[3].y, a.y);
                a.z = fmaf(yv[i].w, wv[3].z, a.z); a.w = fmaf(yv[i].w, wv[3].w, a.w);
                acc[i] = a;
            }
        }
        if (t8 < 7) st(1 - b);
        __syncthreads();
    }
#pragma unroll
    for (int i = 0; i < 4; ++i)
        *(float4*)&out[(size_t)(r0 + rq * 4 + i) * 64 + c4] = acc[i];
}

extern "C" void kernel_launch(void* const* d_in, const int* in_sizes, int n_in,
                              void* d_out, int out_size, void* d_ws, size_t ws_size,
                              hipStream_t stream)
{
    const float* x      = (const float*)d_in[0];
    const int*   adj    = (const int*)  d_in[1];
    const float* W_in   = (const float*)d_in[2];
    const float* W_conv = (const float*)d_in[3];
    const float* b_conv = (const float*)d_in[4];
    const float* W_xp   = (const float*)d_in[5];
    const float* W_dt   = (const float*)d_in[6];
    const float* b_dt   = (const float*)d_in[7];
    const float* A_log  = (const float*)d_in[8];
    const float* Dvec   = (const float*)d_in[9];
    const float* W_out  = (const float*)d_in[10];

    float* ws   = (float*)d_ws;
    float* u    = ws + U_OFF;
    float* sres = ws + SRES_OFF;   // becomes gated y after k3
    float* dB   = ws + DPH_OFF;    // dlt, then dph
    float* dpt  = ws + DPT_OFF;
    float* Bb   = ws + B_OFF;
    float* Cb   = ws + C_OFF;
    float* dAt  = ws + DAT_OFF;
    float* out  = (float*)d_out;

    k1_inproj<<<dim3(16, 128), 256, 0, stream>>>(x, W_in, W_conv, b_conv, u, sres);
    k2a_xproj<<<dim3(512),     128, 0, stream>>>(u, W_xp, dB, Bb, Cb);
    k2b_delta<<<dim3(2048),    256, 0, stream>>>(dB, W_dt, b_dt, adj, A_log, dB, dpt, dAt);
    k3_scan  <<<dim3(16, 128), 256, 0, stream>>>(u, sres, dB, dpt, Bb, Cb, dAt, A_log, Dvec);
    k4_out   <<<dim3(512),     128, 0, stream>>>(sres, W_out, out);
}

// Round 16
// 270.007 us; speedup vs baseline: 1.1914x; 1.1914x over previous
//
#include <hip/hip_runtime.h>
#include <cmath>

#define T_    128
#define F_    64
#define DI    512
#define DS    16
#define NROW  16384   // 128 seqs * 128 t

// workspace layout (float offsets)
#define U_OFF    0u
#define SRES_OFF 8388608u                 // NROW*DI
#define DPH_OFF  16777216u                // NROW*32 (dlt, then dph)
#define DPT_OFF  17301504u                // NROW
#define B_OFF    17317888u                // NROW*16
#define C_OFF    17580032u                // NROW*16
#define DAT_OFF  17842176u                // NROW*16 (precomputed tail exp(dpt*A))
// end = 18104320 floats (~72.4 MB)

__device__ __forceinline__ float silu_f(float v)    { return v / (1.f + __expf(-v)); }
__device__ __forceinline__ float softplus_f(float v){ return (v > 20.f) ? v : log1pf(__expf(v)); }

// ---------------------------------------------------------------------------
// K1 (r5-verified, ~53us): xz = X @ W_in + causal depthwise conv4 + SiLU.
// float4 columns, 8-row t-tile, 4+4-row W ping-pong (~76 VGPR).
// ---------------------------------------------------------------------------
__global__ __launch_bounds__(256) void k1_inproj(
    const float* __restrict__ x, const float* __restrict__ W_in,
    const float* __restrict__ W_conv, const float* __restrict__ b_conv,
    float* __restrict__ u, float* __restrict__ sres)
{
    __shared__ float x_l[11][64];
    const int s   = blockIdx.y;
    const int t0  = blockIdx.x * 8;
    const int tid = threadIdx.x;
    const int c4  = tid * 4;                // column 0..1023

    if (tid < 11 * 16) {
        const int row = tid >> 4, cc = (tid & 15) * 4;
        const int trow = t0 - 3 + row;
        float4 v = make_float4(0.f, 0.f, 0.f, 0.f);
        if (trow >= 0) v = *(const float4*)&x[(size_t)s * (T_ * F_) + trow * F_ + cc];
        *(float4*)&x_l[row][cc] = v;
    }
    __syncthreads();

    float4 acc[11];
#pragma unroll
    for (int i = 0; i < 11; ++i) acc[i] = make_float4(0.f, 0.f, 0.f, 0.f);

    auto compute4 = [&](int f0, const float4 (&wv)[4]) {
#pragma unroll
        for (int tt = 0; tt < 11; ++tt) {
            const float4 xa = *(const float4*)&x_l[tt][f0];
            float4 a = acc[tt];
            a.x = fmaf(xa.x, wv[0].x, a.x); a.y = fmaf(xa.x, wv[0].y, a.y);
            a.z = fmaf(xa.x, wv[0].z, a.z); a.w = fmaf(xa.x, wv[0].w, a.w);
            a.x = fmaf(xa.y, wv[1].x, a.x); a.y = fmaf(xa.y, wv[1].y, a.y);
            a.z = fmaf(xa.y, wv[1].z, a.z); a.w = fmaf(xa.y, wv[1].w, a.w);
            a.x = fmaf(xa.z, wv[2].x, a.x); a.y = fmaf(xa.z, wv[2].y, a.y);
            a.z = fmaf(xa.z, wv[2].z, a.z); a.w = fmaf(xa.z, wv[2].w, a.w);
            a.x = fmaf(xa.w, wv[3].x, a.x); a.y = fmaf(xa.w, wv[3].y, a.y);
            a.z = fmaf(xa.w, wv[3].z, a.z); a.w = fmaf(xa.w, wv[3].w, a.w);
            acc[tt] = a;
        }
    };

    float4 wa[4], wb[4];
#pragma unroll
    for (int j = 0; j < 4; ++j) wa[j] = *(const float4*)&W_in[(size_t)j * 1024 + c4];
    for (int k0 = 0; k0 < 64; k0 += 8) {
#pragma unroll
        for (int j = 0; j < 4; ++j) wb[j] = *(const float4*)&W_in[(size_t)(k0 + 4 + j) * 1024 + c4];
        compute4(k0, wa);
        if (k0 + 8 < 64) {
#pragma unroll
            for (int j = 0; j < 4; ++j) wa[j] = *(const float4*)&W_in[(size_t)(k0 + 8 + j) * 1024 + c4];
        }
        compute4(k0 + 4, wb);
    }

    if (c4 < DI) {
        const float4 wk0 = *(const float4*)&W_conv[(c4 + 0) * 4];
        const float4 wk1 = *(const float4*)&W_conv[(c4 + 1) * 4];
        const float4 wk2 = *(const float4*)&W_conv[(c4 + 2) * 4];
        const float4 wk3 = *(const float4*)&W_conv[(c4 + 3) * 4];
        const float4 bc  = *(const float4*)&b_conv[c4];
#pragma unroll
        for (int i = 0; i < 8; ++i) {
            float4 pre;
            pre.x = bc.x; pre.y = bc.y; pre.z = bc.z; pre.w = bc.w;
            pre.x = fmaf(wk0.x, acc[i].x, pre.x); pre.x = fmaf(wk0.y, acc[i+1].x, pre.x);
            pre.x = fmaf(wk0.z, acc[i+2].x, pre.x); pre.x = fmaf(wk0.w, acc[i+3].x, pre.x);
            pre.y = fmaf(wk1.x, acc[i].y, pre.y); pre.y = fmaf(wk1.y, acc[i+1].y, pre.y);
            pre.y = fmaf(wk1.z, acc[i+2].y, pre.y); pre.y = fmaf(wk1.w, acc[i+3].y, pre.y);
            pre.z = fmaf(wk2.x, acc[i].z, pre.z); pre.z = fmaf(wk2.y, acc[i+1].z, pre.z);
            pre.z = fmaf(wk2.z, acc[i+2].z, pre.z); pre.z = fmaf(wk2.w, acc[i+3].z, pre.z);
            pre.w = fmaf(wk3.x, acc[i].w, pre.w); pre.w = fmaf(wk3.y, acc[i+1].w, pre.w);
            pre.w = fmaf(wk3.z, acc[i+2].w, pre.w); pre.w = fmaf(wk3.w, acc[i+3].w, pre.w);
            float4 o;
            o.x = silu_f(pre.x); o.y = silu_f(pre.y);
            o.z = silu_f(pre.z); o.w = silu_f(pre.w);
            *(float4*)&u[(size_t)(s * T_ + t0 + i) * DI + c4] = o;
        }
    } else {
        const int c = c4 - DI;
#pragma unroll
        for (int i = 0; i < 8; ++i) {
            float4 o;
            o.x = silu_f(acc[i + 3].x); o.y = silu_f(acc[i + 3].y);
            o.z = silu_f(acc[i + 3].z); o.w = silu_f(acc[i + 3].w);
            *(float4*)&sres[(size_t)(s * T_ + t0 + i) * DI + c] = o;
        }
    }
}

// ---------------------------------------------------------------------------
// K2a (v1, r5-verified, ~43us): xdbl = u @ W_xproj -> dlt / B / C. 32-row
// tiles, 512 blocks x 128 thr, KC=64 LDS double-buffer + reg staging.
// ---------------------------------------------------------------------------
__global__ __launch_bounds__(128) void k2a_xproj(
    const float* __restrict__ uin, const float* __restrict__ W_xp,
    float* __restrict__ dlt, float* __restrict__ Bb, float* __restrict__ Cb)
{
    __shared__ float y_l[2][32][68];
    __shared__ float w_l[2][64][64];
    const int tid = threadIdx.x;
    const int rq = tid >> 4, cq = tid & 15;
    const int r0 = blockIdx.x * 32;
    const int c4 = cq * 4;

    float4 yR[4], wR[8];
    auto ld = [&](int kc) {
#pragma unroll
        for (int q = 0; q < 4; ++q) {
            const int i = q * 128 + tid;
            yR[q] = *(const float4*)&uin[(size_t)(r0 + (i >> 4)) * DI + kc + (i & 15) * 4];
        }
#pragma unroll
        for (int q = 0; q < 8; ++q) {
            const int i = q * 128 + tid;
            wR[q] = *(const float4*)&W_xp[(size_t)(kc + (i >> 4)) * 64 + (i & 15) * 4];
        }
    };
    auto st = [&](int b) {
#pragma unroll
        for (int q = 0; q < 4; ++q) {
            const int i = q * 128 + tid;
            *(float4*)&y_l[b][i >> 4][(i & 15) * 4] = yR[q];
        }
#pragma unroll
        for (int q = 0; q < 8; ++q) {
            const int i = q * 128 + tid;
            *(float4*)&w_l[b][i >> 4][(i & 15) * 4] = wR[q];
        }
    };

    float4 acc[4];
#pragma unroll
    for (int i = 0; i < 4; ++i) acc[i] = make_float4(0.f, 0.f, 0.f, 0.f);

    ld(0); st(0); __syncthreads();
    for (int t8 = 0; t8 < 8; ++t8) {
        const int b = t8 & 1;
        if (t8 < 7) ld((t8 + 1) * 64);
#pragma unroll 4
        for (int kk = 0; kk < 64; kk += 4) {
            float4 yv[4], wv[4];
#pragma unroll
            for (int i = 0; i < 4; ++i) yv[i] = *(const float4*)&y_l[b][rq * 4 + i][kk];
#pragma unroll
            for (int j = 0; j < 4; ++j) wv[j] = *(const float4*)&w_l[b][kk + j][c4];
#pragma unroll
            for (int i = 0; i < 4; ++i) {
                float4 a = acc[i];
                a.x = fmaf(yv[i].x, wv[0].x, a.x); a.y = fmaf(yv[i].x, wv[0].y, a.y);
                a.z = fmaf(yv[i].x, wv[0].z, a.z); a.w = fmaf(yv[i].x, wv[0].w, a.w);
                a.x = fmaf(yv[i].y, wv[1].x, a.x); a.y = fmaf(yv[i].y, wv[1].y, a.y);
                a.z = fmaf(yv[i].y, wv[1].z, a.z); a.w = fmaf(yv[i].y, wv[1].w, a.w);
                a.x = fmaf(yv[i].z, wv[2].x, a.x); a.y = fmaf(yv[i].z, wv[2].y, a.y);
                a.z = fmaf(yv[i].z, wv[2].z, a.z); a.w = fmaf(yv[i].z, wv[2].w, a.w);
                a.x = fmaf(yv[i].w, wv[3].x, a.x); a.y = fmaf(yv[i].w, wv[3].y, a.y);
                a.z = fmaf(yv[i].w, wv[3].z, a.z); a.w = fmaf(yv[i].w, wv[3].w, a.w);
                acc[i] = a;
            }
        }
        if (t8 < 7) st(1 - b);
        __syncthreads();
    }
#pragma unroll
    for (int i = 0; i < 4; ++i) {
        const int r = r0 + rq * 4 + i;
        if (c4 < 32)      *(float4*)&dlt[(size_t)r * 32 + c4]        = acc[i];
        else if (c4 < 48) *(float4*)&Bb [(size_t)r * DS + (c4 - 32)] = acc[i];
        else              *(float4*)&Cb [(size_t)r * DS + (c4 - 48)] = acc[i];
    }
}

// ---------------------------------------------------------------------------
// K2b v2 (r10-verified, ~21us): row-split x4, 2048 blocks x 8 rows.
// ---------------------------------------------------------------------------
__global__ __launch_bounds__(256) void k2b_delta(
    const float* __restrict__ dlt_in, const float* __restrict__ W_dt,
    const float* __restrict__ b_dt, const int* __restrict__ adj,
    const float* __restrict__ A_log,
    float* __restrict__ dph, float* __restrict__ dpt, float* __restrict__ dAt)
{
    __shared__ float dl_l[8][32];
    __shared__ float head_l[8][33];
    __shared__ float scrS[4][8];
    __shared__ float st_l[8], stail_l[8];
    __shared__ float adj_l[1024];

    const int tid  = threadIdx.x;
    const int lane = tid & 63, wv4 = tid >> 6;
    const int r0   = blockIdx.x * 8;

    dl_l[tid >> 5][tid & 31] = dlt_in[(size_t)(r0 + (tid >> 5)) * 32 + (tid & 31)];
    for (int i = tid; i < 1024; i += 256) adj_l[i] = (float)adj[i];

    float wdt0[32], wdt1[32];
#pragma unroll
    for (int j = 0; j < 32; ++j) {
        wdt0[j] = W_dt[j * DI + tid];
        wdt1[j] = W_dt[j * DI + tid + 256];
    }
    const float b0 = b_dt[tid], b1 = b_dt[tid + 256];
    __syncthreads();

    for (int r = 0; r < 8; ++r) {
        float a0 = b0, a1 = b1;
#pragma unroll
        for (int jq = 0; jq < 8; ++jq) {
            const float4 dv = *(const float4*)&dl_l[r][jq * 4];
            a0 = fmaf(dv.x, wdt0[jq*4+0], a0); a1 = fmaf(dv.x, wdt1[jq*4+0], a1);
            a0 = fmaf(dv.y, wdt0[jq*4+1], a0); a1 = fmaf(dv.y, wdt1[jq*4+1], a1);
            a0 = fmaf(dv.z, wdt0[jq*4+2], a0); a1 = fmaf(dv.z, wdt1[jq*4+2], a1);
            a0 = fmaf(dv.w, wdt0[jq*4+3], a0); a1 = fmaf(dv.w, wdt1[jq*4+3], a1);
        }
        const float e0 = softplus_f(a0), e1 = softplus_f(a1);
        if (tid < 32) head_l[r][tid] = e0;
        float v = e0 + e1;
#pragma unroll
        for (int off = 32; off > 0; off >>= 1) v += __shfl_down(v, off, 64);
        if (lane == 0) scrS[wv4][r] = v;
    }
    __syncthreads();
    if (tid < 8) {
        const int r = tid;
        const float st = scrS[0][r] + scrS[1][r] + scrS[2][r] + scrS[3][r];
        dpt[r0 + r] = st;
        float sh = 0.f;
#pragma unroll
        for (int j = 0; j < 32; ++j) sh += head_l[r][j];
        st_l[r] = st;
        stail_l[r] = st - sh;
    }
    __syncthreads();
    {   // dph: 8 rows x 32 cols, one per thread
        const int r = tid >> 5, dd = tid & 31;
        float a = stail_l[r];
#pragma unroll
        for (int j = 0; j < 32; ++j) a = fmaf(head_l[r][j], adj_l[j * 32 + dd], a);
        dph[(size_t)(r0 + r) * 32 + dd] = a;
    }
    if (tid < 128) {   // dAt: 8 rows x 16 states
        const int r = tid >> 4, n = tid & 15;
        dAt[(size_t)(r0 + r) * DS + n] = __expf(st_l[r] * (-__expf(A_log[n])));
    }
}

// ---------------------------------------------------------------------------
// K3 (r2-verified, ~42us): selective scan, n-split x4. Each thread owns 4 of
// the 16 states of one channel; y = C.h reduction = 2 shfl_xor adds.
// Grid dim3(8,128): 1024 blocks x 4 waves = 16 waves/CU. NOTE: n-split x8
// (r15) regressed to 94us — shfl count 67M->201M, 3-deep dependent
// ds_bpermute chain per timestep became the critical path (VALU 28%).
// x4 (2 shfls, 4 FMAs per state-quad) is the measured sweet spot.
// ---------------------------------------------------------------------------
#define CH 8
__global__ __launch_bounds__(256, 4) void k3_scan(
    const float* __restrict__ u, float* __restrict__ sres_y,
    const float* __restrict__ dph, const float* __restrict__ dpt,
    const float* __restrict__ Bb, const float* __restrict__ Cb,
    const float* __restrict__ dAt, const float* __restrict__ A_log,
    const float* __restrict__ Dvec)
{
    __shared__ float u_s[2][CH][64];      // 4 KB
    __shared__ float g_s[2][CH][64];      // 4 KB
    __shared__ float B_s[2][CH][16];      // 1 KB
    __shared__ float C_s[2][CH][16];      // 1 KB
    __shared__ float dAt_s[2][CH][16];    // 1 KB
    __shared__ float dph_s[2][CH][32];    // 2 KB
    __shared__ float dpt_s[2][CH];

    const int tid = threadIdx.x;
    const int s   = blockIdx.y;
    const int grp = blockIdx.x;                  // channel group: grp*64 .. +63
    const int dc  = tid >> 2;                    // channel within group (0..63)
    const int n0  = (tid & 3) * 4;               // this thread's 4 states
    const bool isHead = (grp == 0) && (dc < 32); // wave-uniform (waves 0-1)

    const size_t rb = (size_t)s * T_;
    const float* up   = u      + rb * DI + grp * 64;
    float*       gp   = sres_y + rb * DI + grp * 64;
    const float* dphp = dph + rb * 32;
    const float* dptp = dpt + rb;
    const float* Bp   = Bb  + rb * DS;
    const float* Cp   = Cb  + rb * DS;
    const float* dAtp = dAt + rb * DS;

    float4 A0v = make_float4(0.f, 0.f, 0.f, 0.f);
    if (grp == 0) {
        A0v.x = -__expf(A_log[n0 + 0]);
        A0v.y = -__expf(A_log[n0 + 1]);
        A0v.z = -__expf(A_log[n0 + 2]);
        A0v.w = -__expf(A_log[n0 + 3]);
    }
    const float Dd = Dvec[grp * 64 + dc];

    float h[4];
#pragma unroll
    for (int n = 0; n < 4; ++n) h[n] = 0.f;

    float4 ugR, bcR, dphR;
    float  dptR;
    auto issue_loads = [&](int c) {
        if (tid < 128) {                         // u: 8 rows x 16 float4
            const int j = tid >> 4, c4 = (tid & 15) * 4;
            ugR = *(const float4*)&up[(size_t)(c * CH + j) * DI + c4];
        } else {                                 // g: same mapping
            const int t2 = tid - 128;
            const int j = t2 >> 4, c4 = (t2 & 15) * 4;
            ugR = *(const float4*)&gp[(size_t)(c * CH + j) * DI + c4];
        }
        if (tid < 32)        bcR = *(const float4*)&Bp  [(c * CH + (tid >> 2)) * DS + (tid & 3) * 4];
        else if (tid < 64)   bcR = *(const float4*)&Cp  [(c * CH + ((tid - 32) >> 2)) * DS + ((tid - 32) & 3) * 4];
        else if (tid < 96)   bcR = *(const float4*)&dAtp[(c * CH + ((tid - 64) >> 2)) * DS + ((tid - 64) & 3) * 4];
        if (grp == 0 && tid >= 96 && tid < 160) {
            const int t2 = tid - 96;             // 8 rows x 8 float4
            dphR = *(const float4*)&dphp[(size_t)(c * CH + (t2 >> 3)) * 32 + (t2 & 7) * 4];
        }
        if (tid < CH) dptR = dptp[c * CH + tid];
    };
    auto write_lds = [&](int b) {
        if (tid < 128) {
            const int j = tid >> 4, c4 = (tid & 15) * 4;
            *(float4*)&u_s[b][j][c4] = ugR;
        } else {
            const int t2 = tid - 128;
            const int j = t2 >> 4, c4 = (t2 & 15) * 4;
            *(float4*)&g_s[b][j][c4] = ugR;
        }
        if (tid < 32)        *(float4*)&B_s  [b][tid >> 2][(tid & 3) * 4] = bcR;
        else if (tid < 64)   *(float4*)&C_s  [b][(tid - 32) >> 2][((tid - 32) & 3) * 4] = bcR;
        else if (tid < 96)   *(float4*)&dAt_s[b][(tid - 64) >> 2][((tid - 64) & 3) * 4] = bcR;
        if (grp == 0 && tid >= 96 && tid < 160) {
            const int t2 = tid - 96;
            *(float4*)&dph_s[b][t2 >> 3][(t2 & 7) * 4] = dphR;
        }
        if (tid < CH) dpt_s[b][tid] = dptR;
    };

    issue_loads(0); write_lds(0); __syncthreads();

    float yr = 0.f;
    for (int c = 0; c < T_ / CH; ++c) {
        const int b = c & 1;
        if (c + 1 < T_ / CH) issue_loads(c + 1);
#pragma unroll
        for (int j = 0; j < CH; ++j) {
            const float uv = u_s[b][j][dc];
            const float gv = g_s[b][j][dc];
            float dp;
            float4 av;
            if (isHead) {
                dp = dph_s[b][j][dc];
                av.x = __expf(dp * A0v.x);
                av.y = __expf(dp * A0v.y);
                av.z = __expf(dp * A0v.z);
                av.w = __expf(dp * A0v.w);
            } else {
                dp = dpt_s[b][j];
                av = *(const float4*)&dAt_s[b][j][n0];
            }
            const float4 Bv = *(const float4*)&B_s[b][j][n0];
            const float4 Cv = *(const float4*)&C_s[b][j][n0];
            const float du = dp * uv;
            h[0] = fmaf(av.x, h[0], du * Bv.x); float y = h[0] * Cv.x;
            h[1] = fmaf(av.y, h[1], du * Bv.y); y = fmaf(h[1], Cv.y, y);
            h[2] = fmaf(av.z, h[2], du * Bv.z); y = fmaf(h[2], Cv.z, y);
            h[3] = fmaf(av.w, h[3], du * Bv.w); y = fmaf(h[3], Cv.w, y);
            y += __shfl_xor(y, 1, 64);           // sum across the channel quad
            y += __shfl_xor(y, 2, 64);
            const float yf = fmaf(uv, Dd, y) * gv;
            if ((j & 3) == (tid & 3)) yr = yf;   // round-robin keep
            if ((j & 3) == 3) {                  // each lane writes its kept t
                gp[(size_t)(c * CH + (j - 3) + (tid & 3)) * DI + dc] = yr;
            }
        }
        if (c + 1 < T_ / CH) write_lds(1 - b);
        __syncthreads();
    }
}

// ---------------------------------------------------------------------------
// K4 (v1, r5-verified, ~43us): out = y @ W_out. Mirror of k2a v1.
// ---------------------------------------------------------------------------
__global__ __launch_bounds__(128) void k4_out(
    const float* __restrict__ y, const float* __restrict__ W_out,
    float* __restrict__ out)
{
    __shared__ float y_l[2][32][68];
    __shared__ float w_l[2][64][64];
    const int tid = threadIdx.x;
    const int rq = tid >> 4, cq = tid & 15;
    const int r0 = blockIdx.x * 32;
    const int c4 = cq * 4;

    float4 yR[4], wR[8];
    auto ld = [&](int kc) {
#pragma unroll
        for (int q = 0; q < 4; ++q) {
            const int i = q * 128 + tid;
            yR[q] = *(const float4*)&y[(size_t)(r0 + (i >> 4)) * DI + kc + (i & 15) * 4];
        }
#pragma unroll
        for (int q = 0; q < 8; ++q) {
            const int i = q * 128 + tid;
            wR[q] = *(const float4*)&W_out[(size_t)(kc + (i >> 4)) * 64 + (i & 15) * 4];
        }
    };
    auto st = [&](int b) {
#pragma unroll
        for (int q = 0; q < 4; ++q) {
            const int i = q * 128 + tid;
            *(float4*)&y_l[b][i >> 4][(i & 15) * 4] = yR[q];
        }
#pragma unroll
        for (int q = 0; q < 8; ++q) {
            const int i = q * 128 + tid;
            *(float4*)&w_l[b][i >> 4][(i & 15) * 4] = wR[q];
        }
    };

    float4 acc[4];
#pragma unroll
    for (int i = 0; i < 4; ++i) acc[i] = make_float4(0.f, 0.f, 0.f, 0.f);

    ld(0); st(0); __syncthreads();
    for (int t8 = 0; t8 < 8; ++t8) {
        const int b = t8 & 1;
        if (t8 < 7) ld((t8 + 1) * 64);
#pragma unroll 4
        for (int kk = 0; kk < 64; kk += 4) {
            float4 yv[4], wv[4];
#pragma unroll
            for (int i = 0; i < 4; ++i) yv[i] = *(const float4*)&y_l[b][rq * 4 + i][kk];
#pragma unroll
            for (int j = 0; j < 4; ++j) wv[j] = *(const float4*)&w_l[b][kk + j][c4];
#pragma unroll
            for (int i = 0; i < 4; ++i) {
                float4 a = acc[i];
                a.x = fmaf(yv[i].x, wv[0].x, a.x); a.y = fmaf(yv[i].x, wv[0].y, a.y);
                a.z = fmaf(yv[i].x, wv[0].z, a.z); a.w = fmaf(yv[i].x, wv[0].w, a.w);
                a.x = fmaf(yv[i].y, wv[1].x, a.x); a.y = fmaf(yv[i].y, wv[1].y, a.y);
                a.z = fmaf(yv[i].y, wv[1].z, a.z); a.w = fmaf(yv[i].y, wv[1].w, a.w);
                a.x = fmaf(yv[i].z, wv[2].x, a.x); a.y = fmaf(yv[i].z, wv[2].y, a.y);
                a.z = fmaf(yv[i].z, wv[2].z, a.z); a.w = fmaf(yv[i].z, wv[2].w, a.w);
                a.x = fmaf(yv[i].w, wv[3].x, a.x); a.y = fmaf(yv[i].w, wv[3].y, a.y);
                a.z = fmaf(yv[i].w, wv[3].z, a.z); a.w = fmaf(yv[i].w, wv[3].w, a.w);
                acc[i] = a;
            }
        }
        if (t8 < 7) st(1 - b);
        __syncthreads();
    }
#pragma unroll
    for (int i = 0; i < 4; ++i)
        *(float4*)&out[(size_t)(r0 + rq * 4 + i) * 64 + c4] = acc[i];
}

extern "C" void kernel_launch(void* const* d_in, const int* in_sizes, int n_in,
                              void* d_out, int out_size, void* d_ws, size_t ws_size,
                              hipStream_t stream)
{
    const float* x      = (const float*)d_in[0];
    const int*   adj    = (const int*)  d_in[1];
    const float* W_in   = (const float*)d_in[2];
    const float* W_conv = (const float*)d_in[3];
    const float* b_conv = (const float*)d_in[4];
    const float* W_xp   = (const float*)d_in[5];
    const float* W_dt   = (const float*)d_in[6];
    const float* b_dt   = (const float*)d_in[7];
    const float* A_log  = (const float*)d_in[8];
    const float* Dvec   = (const float*)d_in[9];
    const float* W_out  = (const float*)d_in[10];

    float* ws   = (float*)d_ws;
    float* u    = ws + U_OFF;
    float* sres = ws + SRES_OFF;   // becomes gated y after k3
    float* dB   = ws + DPH_OFF;    // dlt, then dph
    float* dpt  = ws + DPT_OFF;
    float* Bb   = ws + B_OFF;
    float* Cb   = ws + C_OFF;
    float* dAt  = ws + DAT_OFF;
    float* out  = (float*)d_out;

    k1_inproj<<<dim3(16, 128), 256, 0, stream>>>(x, W_in, W_conv, b_conv, u, sres);
    k2a_xproj<<<dim3(512),     128, 0, stream>>>(u, W_xp, dB, Bb, Cb);
    k2b_delta<<<dim3(2048),    256, 0, stream>>>(dB, W_dt, b_dt, adj, A_log, dB, dpt, dAt);
    k3_scan  <<<dim3(8, 128),  256, 0, stream>>>(u, sres, dB, dpt, Bb, Cb, dAt, A_log, Dvec);
    k4_out   <<<dim3(512),     128, 0, stream>>>(sres, W_out, out);
}